// Round 1
// baseline (456.419 us; speedup 1.0000x reference)
//
#include <hip/hip_runtime.h>

typedef unsigned short u16;
typedef u16 u16x2 __attribute__((ext_vector_type(2)));
typedef u16 u16x4 __attribute__((ext_vector_type(4)));
typedef u16 u16x8 __attribute__((ext_vector_type(8)));
typedef __bf16 bf16x8 __attribute__((ext_vector_type(8)));
typedef float f32x4 __attribute__((ext_vector_type(4)));
typedef float f32x2 __attribute__((ext_vector_type(2)));

#define MFMA16(A, B, C) __builtin_amdgcn_mfma_f32_16x16x32_bf16(A, B, C, 0, 0, 0)

// Constants: B=2, S=2048, E=512, H=8, HD=64
#define SB 2
#define SS 2048
#define SE 512
#define SH 8
#define SHD 64

__device__ __forceinline__ u16 f2b(float f) {
  union { float f; unsigned u; } v;
  v.f = f;
  unsigned r = v.u + 0x7FFFu + ((v.u >> 16) & 1u);  // RNE to bf16
  return (u16)(r >> 16);
}

__device__ __forceinline__ bf16x8 as_bf16x8(u16x8 v) {
  return __builtin_bit_cast(bf16x8, v);
}

// ---------------------------------------------------------------------------
// QKV projection: X[4096,512]f32 @ Wqkv[512,1536]f32 + bqkv
//   -> Q bf16 [B,H,S,64] (pre-scaled by 1/8), K bf16 [B,H,S,64],
//      Vt bf16 [B,H,64,S]  (V transposed for PV B-fragments)
// 64x64 tile, BK=32, 256 threads (4 waves, each 32x32 via 2x2 16x16 tiles).
// ---------------------------------------------------------------------------
__global__ __launch_bounds__(256, 4)
void qkv_kernel(const float* __restrict__ X, const float* __restrict__ W,
                const float* __restrict__ bias, u16* __restrict__ Q,
                u16* __restrict__ K, u16* __restrict__ Vt)
{
  __shared__ __align__(16) u16 As[64 * 32];   // [m][k], stride 32
  __shared__ __align__(16) u16 Bs[64 * 40];   // [n][k] transposed, stride 40 (pad)
  const int tid  = threadIdx.x;
  const int lane = tid & 63, wave = tid >> 6, quad = lane >> 4, l16 = lane & 15;
  const int m0 = blockIdx.y * 64, n0 = blockIdx.x * 64;
  const int wr = (wave >> 1) * 32, wc = (wave & 1) * 32;
  const int arow = tid >> 2, acq = (tid & 3) * 4;
  const int bkr = tid >> 4, bnc = (tid & 15) * 4;

  const f32x4 z4 = {0.f, 0.f, 0.f, 0.f};
  f32x4 acc[2][2];
  acc[0][0] = z4; acc[0][1] = z4; acc[1][0] = z4; acc[1][1] = z4;

  for (int k0 = 0; k0 < 512; k0 += 32) {
    const float4 a0 = *(const float4*)&X[(m0 + arow) * 512 + k0 + acq];
    const float4 a1 = *(const float4*)&X[(m0 + arow) * 512 + k0 + 16 + acq];
    const float4 b0 = *(const float4*)&W[(k0 + bkr) * 1536 + n0 + bnc];
    const float4 b1 = *(const float4*)&W[(k0 + 16 + bkr) * 1536 + n0 + bnc];
    __syncthreads();
    u16x4 t0, t1;
    t0[0] = f2b(a0.x); t0[1] = f2b(a0.y); t0[2] = f2b(a0.z); t0[3] = f2b(a0.w);
    t1[0] = f2b(a1.x); t1[1] = f2b(a1.y); t1[2] = f2b(a1.z); t1[3] = f2b(a1.w);
    *(u16x4*)&As[arow * 32 + acq]      = t0;
    *(u16x4*)&As[arow * 32 + 16 + acq] = t1;
    Bs[(bnc + 0) * 40 + bkr]      = f2b(b0.x);
    Bs[(bnc + 1) * 40 + bkr]      = f2b(b0.y);
    Bs[(bnc + 2) * 40 + bkr]      = f2b(b0.z);
    Bs[(bnc + 3) * 40 + bkr]      = f2b(b0.w);
    Bs[(bnc + 0) * 40 + bkr + 16] = f2b(b1.x);
    Bs[(bnc + 1) * 40 + bkr + 16] = f2b(b1.y);
    Bs[(bnc + 2) * 40 + bkr + 16] = f2b(b1.z);
    Bs[(bnc + 3) * 40 + bkr + 16] = f2b(b1.w);
    __syncthreads();
    bf16x8 af0 = as_bf16x8(*(const u16x8*)&As[(wr + l16) * 32 + quad * 8]);
    bf16x8 af1 = as_bf16x8(*(const u16x8*)&As[(wr + 16 + l16) * 32 + quad * 8]);
    bf16x8 bf0 = as_bf16x8(*(const u16x8*)&Bs[(wc + l16) * 40 + quad * 8]);
    bf16x8 bf1 = as_bf16x8(*(const u16x8*)&Bs[(wc + 16 + l16) * 40 + quad * 8]);
    acc[0][0] = MFMA16(af0, bf0, acc[0][0]);
    acc[0][1] = MFMA16(af0, bf1, acc[0][1]);
    acc[1][0] = MFMA16(af1, bf0, acc[1][0]);
    acc[1][1] = MFMA16(af1, bf1, acc[1][1]);
  }

  // Epilogue: scatter into Q (scaled), K, Vt (transposed)
#pragma unroll
  for (int tm = 0; tm < 2; tm++) {
#pragma unroll
    for (int tn = 0; tn < 2; tn++) {
#pragma unroll
      for (int r = 0; r < 4; r++) {
        const int gm = m0 + wr + tm * 16 + quad * 4 + r;   // row in [0,4096)
        const int gn = n0 + wc + tn * 16 + l16;            // col in [0,1536)
        const float v = acc[tm][tn][r] + bias[gn];
        const int bb = gm >> 11, s = gm & 2047;
        const int hh = gn / 192, j = gn - hh * 192;
        const int bh = bb * SH + hh;
        if (j < 64)
          Q[(bh * SS + s) * SHD + j] = f2b(v * 0.125f);
        else if (j < 128)
          K[(bh * SS + s) * SHD + (j - 64)] = f2b(v);
        else
          Vt[(bh * SHD + (j - 128)) * SS + s] = f2b(v);
      }
    }
  }
}

// ---------------------------------------------------------------------------
// Fused attention: per block = one (b,h), 16 query rows, all 2048 keys.
// 512 threads = 8 waves; wave w owns key columns [w*256, w*256+256).
// Scores in C-frags (64 f32/lane), softmax via quad-shuffle + LDS,
// P -> d_out (fp32) + LDS (bf16, A-layout round-trip), PV -> values bf16.
// ---------------------------------------------------------------------------
__global__ __launch_bounds__(512, 2)
void attn_kernel(const u16* __restrict__ Q, const u16* __restrict__ K,
                 const u16* __restrict__ Vt, u16* __restrict__ values,
                 float* __restrict__ attn)
{
  __shared__ __align__(16) u16 p_lds[8 * 16 * 264];  // 67584 B, stride 264 (pad 8)
  __shared__ float redmax[8][16];
  __shared__ float redsum[8][16];

  const int tid  = threadIdx.x;
  const int lane = tid & 63, wave = tid >> 6, quad = lane >> 4, l16 = lane & 15;
  const int q0 = blockIdx.x * 16;
  const int h = blockIdx.y, b = blockIdx.z, bh = b * SH + h;

  const u16* Qb = Q + bh * SS * SHD;
  const u16* Kb = K + bh * SS * SHD;
  const u16* Vb = Vt + bh * SHD * SS;

  // Q A-frags (same 16 rows for every wave), d in [0,32) and [32,64)
  const bf16x8 aq0 = as_bf16x8(*(const u16x8*)&Qb[(q0 + l16) * SHD + quad * 8]);
  const bf16x8 aq1 = as_bf16x8(*(const u16x8*)&Qb[(q0 + l16) * SHD + 32 + quad * 8]);

  // ---- scores: 16 tiles of 16x16 per wave ----
  f32x4 acc[16];
#pragma unroll
  for (int ct = 0; ct < 16; ct++) {
    const int kb = wave * 256 + ct * 16;
    bf16x8 bk0 = as_bf16x8(*(const u16x8*)&Kb[(kb + l16) * SHD + quad * 8]);
    bf16x8 bk1 = as_bf16x8(*(const u16x8*)&Kb[(kb + l16) * SHD + 32 + quad * 8]);
    f32x4 c = {0.f, 0.f, 0.f, 0.f};
    c = MFMA16(aq0, bk0, c);
    c = MFMA16(aq1, bk1, c);
    acc[ct] = c;
  }

  // ---- row max (rows = quad*4+r), across 16 lanes then 8 waves ----
  float mx[4];
#pragma unroll
  for (int r = 0; r < 4; r++) mx[r] = acc[0][r];
#pragma unroll
  for (int ct = 1; ct < 16; ct++)
#pragma unroll
    for (int r = 0; r < 4; r++) mx[r] = fmaxf(mx[r], acc[ct][r]);
#pragma unroll
  for (int off = 1; off < 16; off <<= 1)
#pragma unroll
    for (int r = 0; r < 4; r++) mx[r] = fmaxf(mx[r], __shfl_xor(mx[r], off));
  if (l16 == 0) {
#pragma unroll
    for (int r = 0; r < 4; r++) redmax[wave][quad * 4 + r] = mx[r];
  }
  __syncthreads();
  float gm[4];
#pragma unroll
  for (int r = 0; r < 4; r++) {
    float m = redmax[0][quad * 4 + r];
#pragma unroll
    for (int w = 1; w < 8; w++) m = fmaxf(m, redmax[w][quad * 4 + r]);
    gm[r] = m;
  }

  // ---- exp + row sum ----
  float ls[4] = {0.f, 0.f, 0.f, 0.f};
#pragma unroll
  for (int ct = 0; ct < 16; ct++)
#pragma unroll
    for (int r = 0; r < 4; r++) {
      const float p = __expf(acc[ct][r] - gm[r]);
      acc[ct][r] = p;
      ls[r] += p;
    }
#pragma unroll
  for (int off = 1; off < 16; off <<= 1)
#pragma unroll
    for (int r = 0; r < 4; r++) ls[r] += __shfl_xor(ls[r], off);
  if (l16 == 0) {
#pragma unroll
    for (int r = 0; r < 4; r++) redsum[wave][quad * 4 + r] = ls[r];
  }
  __syncthreads();
  float inv[4];
#pragma unroll
  for (int r = 0; r < 4; r++) {
    float s = redsum[0][quad * 4 + r];
#pragma unroll
    for (int w = 1; w < 8; w++) s += redsum[w][quad * 4 + r];
    inv[r] = 1.f / s;
  }

  // ---- normalize: write fp32 P to d_out, bf16 P to LDS ----
  float* attn_b = attn + (bh * SS + q0) * SS;
#pragma unroll
  for (int ct = 0; ct < 16; ct++) {
    const int col = wave * 256 + ct * 16 + l16;
#pragma unroll
    for (int r = 0; r < 4; r++) {
      const float p = acc[ct][r] * inv[r];
      attn_b[(quad * 4 + r) * SS + col] = p;
      p_lds[(wave * 16 + quad * 4 + r) * 264 + ct * 16 + l16] = f2b(p);
    }
  }

  // ---- PV: each wave contracts its own 256 columns (reads only own LDS chunk,
  //      wave-coherent, no barrier needed) ----
  f32x4 oacc[4];
#pragma unroll
  for (int nt = 0; nt < 4; nt++) oacc[nt] = (f32x4){0.f, 0.f, 0.f, 0.f};
#pragma unroll
  for (int kc = 0; kc < 8; kc++) {
    bf16x8 pa = as_bf16x8(*(const u16x8*)&p_lds[(wave * 16 + l16) * 264 + kc * 32 + quad * 8]);
    const int sb = wave * 256 + kc * 32 + quad * 8;
#pragma unroll
    for (int nt = 0; nt < 4; nt++) {
      bf16x8 vb = as_bf16x8(*(const u16x8*)&Vb[(nt * 16 + l16) * SS + sb]);
      oacc[nt] = MFMA16(pa, vb, oacc[nt]);
    }
  }

  // ---- reduce 8 wave-partials through (reused) LDS ----
  __syncthreads();  // all waves done reading p_lds
  float* opart = (float*)p_lds;  // [8][16][64] f32 = 32 KB
#pragma unroll
  for (int nt = 0; nt < 4; nt++)
#pragma unroll
    for (int r = 0; r < 4; r++)
      opart[(wave * 16 + quad * 4 + r) * 64 + nt * 16 + l16] = oacc[nt][r];
  __syncthreads();

  const int q = tid >> 5, d0 = (tid & 31) * 2;
  f32x2 s2 = {0.f, 0.f};
#pragma unroll
  for (int w = 0; w < 8; w++) s2 += *(const f32x2*)&opart[(w * 16 + q) * 64 + d0];
  u16x2 o2;
  o2[0] = f2b(s2[0]);
  o2[1] = f2b(s2[1]);
  // values layout [B,S,H,64] so O-proj reads rows of [B*S, E]
  *(u16x2*)&values[((b * SS + q0 + q) * SH + h) * SHD + d0] = o2;
}

// ---------------------------------------------------------------------------
// O projection: values bf16 [4096,512] @ Wo[512,512]f32 + bo -> o fp32 [4096,512]
// ---------------------------------------------------------------------------
__global__ __launch_bounds__(256, 4)
void oproj_kernel(const u16* __restrict__ Vv, const float* __restrict__ W,
                  const float* __restrict__ bias, float* __restrict__ Out)
{
  __shared__ __align__(16) u16 As[64 * 32];
  __shared__ __align__(16) u16 Bs[64 * 40];
  const int tid  = threadIdx.x;
  const int lane = tid & 63, wave = tid >> 6, quad = lane >> 4, l16 = lane & 15;
  const int m0 = blockIdx.y * 64, n0 = blockIdx.x * 64;
  const int wr = (wave >> 1) * 32, wc = (wave & 1) * 32;
  const int arow = tid >> 2, acq = (tid & 3) * 8;
  const int bkr = tid >> 4, bnc = (tid & 15) * 4;

  const f32x4 z4 = {0.f, 0.f, 0.f, 0.f};
  f32x4 acc[2][2];
  acc[0][0] = z4; acc[0][1] = z4; acc[1][0] = z4; acc[1][1] = z4;

  for (int k0 = 0; k0 < 512; k0 += 32) {
    const u16x8 a = *(const u16x8*)&Vv[(m0 + arow) * 512 + k0 + acq];
    const float4 b0 = *(const float4*)&W[(k0 + bkr) * 512 + n0 + bnc];
    const float4 b1 = *(const float4*)&W[(k0 + 16 + bkr) * 512 + n0 + bnc];
    __syncthreads();
    *(u16x8*)&As[arow * 32 + acq] = a;
    Bs[(bnc + 0) * 40 + bkr]      = f2b(b0.x);
    Bs[(bnc + 1) * 40 + bkr]      = f2b(b0.y);
    Bs[(bnc + 2) * 40 + bkr]      = f2b(b0.z);
    Bs[(bnc + 3) * 40 + bkr]      = f2b(b0.w);
    Bs[(bnc + 0) * 40 + bkr + 16] = f2b(b1.x);
    Bs[(bnc + 1) * 40 + bkr + 16] = f2b(b1.y);
    Bs[(bnc + 2) * 40 + bkr + 16] = f2b(b1.z);
    Bs[(bnc + 3) * 40 + bkr + 16] = f2b(b1.w);
    __syncthreads();
    bf16x8 af0 = as_bf16x8(*(const u16x8*)&As[(wr + l16) * 32 + quad * 8]);
    bf16x8 af1 = as_bf16x8(*(const u16x8*)&As[(wr + 16 + l16) * 32 + quad * 8]);
    bf16x8 bf0 = as_bf16x8(*(const u16x8*)&Bs[(wc + l16) * 40 + quad * 8]);
    bf16x8 bf1 = as_bf16x8(*(const u16x8*)&Bs[(wc + 16 + l16) * 40 + quad * 8]);
    acc[0][0] = MFMA16(af0, bf0, acc[0][0]);
    acc[0][1] = MFMA16(af0, bf1, acc[0][1]);
    acc[1][0] = MFMA16(af1, bf0, acc[1][0]);
    acc[1][1] = MFMA16(af1, bf1, acc[1][1]);
  }

#pragma unroll
  for (int tm = 0; tm < 2; tm++)
#pragma unroll
    for (int tn = 0; tn < 2; tn++)
#pragma unroll
      for (int r = 0; r < 4; r++) {
        const int gm = m0 + wr + tm * 16 + quad * 4 + r;
        const int gn = n0 + wc + tn * 16 + l16;
        Out[gm * 512 + gn] = acc[tm][tn][r] + bias[gn];
      }
}

// ---------------------------------------------------------------------------
extern "C" void kernel_launch(void* const* d_in, const int* in_sizes, int n_in,
                              void* d_out, int out_size, void* d_ws, size_t ws_size,
                              hipStream_t stream) {
  const float* X    = (const float*)d_in[0];
  const float* Wqkv = (const float*)d_in[1];
  const float* bqkv = (const float*)d_in[2];
  const float* Wo   = (const float*)d_in[3];
  const float* bo   = (const float*)d_in[4];

  float* o_out    = (float*)d_out;                       // [2,2048,512]
  float* attn_out = o_out + SB * SS * SE;                // [2,8,2048,2048]

  const size_t QKV_ELEMS = (size_t)SB * SH * SS * SHD;   // 2,097,152 per tensor
  u16* Q      = (u16*)d_ws;
  u16* K      = Q + QKV_ELEMS;
  u16* Vt     = K + QKV_ELEMS;
  u16* values = Vt + QKV_ELEMS;

  // QKV projection: M=4096 (64 m-blocks), N=1536 (24 n-blocks)
  qkv_kernel<<<dim3(24, 64), 256, 0, stream>>>(X, Wqkv, bqkv, Q, K, Vt);
  // Attention: 128 row-blocks x 8 heads x 2 batches
  attn_kernel<<<dim3(128, 8, 2), 512, 0, stream>>>(Q, K, Vt, values, attn_out);
  // O projection: M=4096 (64), N=512 (8)
  oproj_kernel<<<dim3(8, 64), 256, 0, stream>>>(values, Wo, bo, o_out);
}